// Round 14
// baseline (1483.114 us; speedup 1.0000x reference)
//
#include <hip/hip_runtime.h>
#include <hip/hip_bf16.h>
#include <stdint.h>

// QuantizedLinear: Y[M][N] = scale * (X[M][K] @ W[N][K]^T) + bias[N]
// M=8192, K=4096, N=16384. X fp32, W int32 (harness widens int8), out fp32.
// Round 14: 2-blocks-per-CU geometry. r8-r13 showed the residual stall is
// whole-CU lockstep (1 block/CU at 128 KiB LDS): every barrier idles all 8
// waves. This round: 128x128 tile, 4 waves, 64 KiB LDS -> 2 independent
// blocks/CU (16 waves/CU); block B computes through block A's barrier
// drain (m114 cross-block overlap). Epoch machinery is r11's verbatim,
// scaled: 8 ds_reads + 16 MFMAs per epoch, {2 reads, 4 MFMA}x4 interleave,
// same WAIT4 vmcnt ring (re-verified), 16x16x32 MFMA (contiguous frag
// reads + 64B-coalesced staging — the conflict-free combination).

typedef __attribute__((ext_vector_type(4))) float f32x4;
typedef __attribute__((ext_vector_type(4))) int i32x4;
typedef __attribute__((ext_vector_type(8))) short bf16x8s;
typedef __attribute__((ext_vector_type(4))) unsigned int u32x4;

__device__ __forceinline__ uint32_t f2bf_rne(float f) {
  uint32_t x = __float_as_uint(f);
  return (x + 0x7FFFu + ((x >> 16) & 1u)) >> 16;
}
__device__ __forceinline__ uint32_t pk2_rne(float lo, float hi) {
  return f2bf_rne(lo) | (f2bf_rne(hi) << 16);
}
__device__ __forceinline__ uint32_t pk2_trunc(float lo, float hi) {
  return (__float_as_uint(lo) >> 16) | (__float_as_uint(hi) & 0xFFFF0000u);
}

#define GLOAD_LDS16(g, l)                                        \
  __builtin_amdgcn_global_load_lds(                              \
      (const __attribute__((address_space(1))) void*)(g),        \
      (__attribute__((address_space(3))) void*)(l), 16, 0, 0)

// ---------------- conversion kernels (NT loads: inputs are read-once) ------
__global__ __launch_bounds__(256) void conv_x_kernel(
    const float* __restrict__ x, uint16_t* __restrict__ out, int n8) {
  const int stride = blockDim.x * gridDim.x;
  for (int i = blockIdx.x * blockDim.x + threadIdx.x; i < n8; i += stride) {
    f32x4 v0 = __builtin_nontemporal_load((const f32x4*)x + i * 2);
    f32x4 v1 = __builtin_nontemporal_load((const f32x4*)x + i * 2 + 1);
    u32x4 o;
    o.x = pk2_rne(v0.x, v0.y);
    o.y = pk2_rne(v0.z, v0.w);
    o.z = pk2_rne(v1.x, v1.y);
    o.w = pk2_rne(v1.z, v1.w);
    ((u32x4*)out)[i] = o;
  }
}

__global__ __launch_bounds__(256) void conv_w_kernel(
    const int32_t* __restrict__ w, uint16_t* __restrict__ out, int n8) {
  const int stride = blockDim.x * gridDim.x;
  for (int i = blockIdx.x * blockDim.x + threadIdx.x; i < n8; i += stride) {
    i32x4 v0 = __builtin_nontemporal_load((const i32x4*)w + i * 2);
    i32x4 v1 = __builtin_nontemporal_load((const i32x4*)w + i * 2 + 1);
    u32x4 o;
    o.x = pk2_trunc((float)v0.x, (float)v0.y);
    o.y = pk2_trunc((float)v0.z, (float)v0.w);
    o.z = pk2_trunc((float)v1.x, (float)v1.y);
    o.w = pk2_trunc((float)v1.z, (float)v1.w);
    ((u32x4*)out)[i] = o;
  }
}

// ---------------- 128x128 GEMM, 4 waves, 2 blocks/CU ----------------------
// LDS (65536 B): buf b at b*32768; within buf: A-half kk at kk*8192,
// B-half kk at 16384 + kk*8192. Each half-unit = 128 rows x 64 B row-major
// (linear: slot = row*64 + col). Frag reads: 64 lanes cover 16 rows x 64 B
// contiguous (conflict-free, r11 pattern). Staging: thread t loads global
// (row=t>>2, col=(t&3)*16) -> dest tid*16 linear, 64 B/row coalesced.

#define PIN() __builtin_amdgcn_sched_barrier(0)

#define BARRIER()                 \
  PIN();                          \
  __builtin_amdgcn_s_barrier();   \
  PIN()

#define WAIT4  asm volatile("s_waitcnt vmcnt(4)" ::: "memory"); PIN()
#define WAIT0  asm volatile("s_waitcnt vmcnt(0)" ::: "memory"); PIN()
#define WAITL0 asm volatile("s_waitcnt lgkmcnt(0)" ::: "memory"); PIN()

// One half-unit (A or B, one K-half): 128 rows x 64 B = 8 KB, 2 gloads.
#define STAGE(mat_base, koffb, ldsbase)                                      \
  {                                                                          \
    GLOAD_LDS16((mat_base) + (size_t)srow * RSB + (koffb) + skch,            \
                (ldsbase) + tid * 16);                                       \
    GLOAD_LDS16((mat_base) + (size_t)(srow + 64) * RSB + (koffb) + skch,     \
                (ldsbase) + 4096 + tid * 16);                                \
  }

#define ABLK(buf, kk) ((buf) + (kk) * 8192)
#define BBLK(buf, kk) ((buf) + 16384 + (kk) * 8192)

// inline-asm ds_read_b128 — invisible to the compiler's waitcnt pass
#define DSR(dst, addr, OFF)                                                  \
  asm volatile("ds_read_b128 %0, %1 offset:" OFF : "=v"(dst) : "v"(addr))

// 8 reads: 4 A-frags + 4 B-frags (frag stride 16 rows = 1024 B)
#define READ8(da, db, blkoff)                                                \
  {                                                                          \
    uint32_t _aa = aoff + (blkoff), _bb = boff + (blkoff);                   \
    DSR(da[0], _aa, "0");    DSR(da[1], _aa, "1024");                        \
    DSR(da[2], _aa, "2048"); DSR(da[3], _aa, "3072");                        \
    DSR(db[0], _bb, "0");    DSR(db[1], _bb, "1024");                        \
    DSR(db[2], _bb, "2048"); DSR(db[3], _bb, "3072");                        \
  }

#define MFMA4(av, bv, j)                                                     \
  _Pragma("unroll") for (int ni = 0; ni < 4; ++ni)                           \
    acc[j][ni] = __builtin_amdgcn_mfma_f32_16x16x32_bf16(                    \
        av[j], bv[ni], acc[j][ni], 0, 0, 0);

// One epoch: 16 MFMAs on (av,bv) interleaved with the 8 ds_reads filling
// (xa,xb) for the NEXT epoch (prefetch target half-block at blkoff).
#define EPOCH_ILV(av, bv, xa, xb, blkoff)                                    \
  {                                                                          \
    uint32_t _aa = aoff + (blkoff), _bb = boff + (blkoff);                   \
    __builtin_amdgcn_s_setprio(1);                                           \
    DSR(xa[0], _aa, "0");    DSR(xa[1], _aa, "1024");   PIN();               \
    MFMA4(av, bv, 0);                                   PIN();               \
    DSR(xa[2], _aa, "2048"); DSR(xa[3], _aa, "3072");   PIN();               \
    MFMA4(av, bv, 1);                                   PIN();               \
    DSR(xb[0], _bb, "0");    DSR(xb[1], _bb, "1024");   PIN();               \
    MFMA4(av, bv, 2);                                   PIN();               \
    DSR(xb[2], _bb, "2048"); DSR(xb[3], _bb, "3072");   PIN();               \
    MFMA4(av, bv, 3);                                                        \
    __builtin_amdgcn_s_setprio(0);                                           \
  }

// last epoch: plain 16 MFMAs, no prefetch
#define MFMA16(av, bv)                                                       \
  __builtin_amdgcn_s_setprio(1);                                             \
  _Pragma("unroll") for (int j = 0; j < 4; ++j)                              \
    _Pragma("unroll") for (int ni = 0; ni < 4; ++ni)                         \
      acc[j][ni] = __builtin_amdgcn_mfma_f32_16x16x32_bf16(                  \
          av[j], bv[ni], acc[j][ni], 0, 0, 0);                               \
  __builtin_amdgcn_s_setprio(0);

__global__ __launch_bounds__(256, 2) void qlinear_gemm_128_kernel(
    const uint16_t* __restrict__ Xb,  // [M][K] bf16
    const uint16_t* __restrict__ Wb,  // [N][K] bf16
    const float* __restrict__ scalep,
    const float* __restrict__ bias,
    float* __restrict__ Y)
{
  constexpr int N = 16384, K = 4096;
  constexpr int RSB = K * 2;   // panel row stride, bytes
  constexpr int NT = K / 64;   // 64 K-tiles

  extern __shared__ __align__(16) char lds[];  // 65536 B

  const int tid  = threadIdx.x;
  const int lane = tid & 63;
  const int wid  = tid >> 6;   // 0..3
  const int wr   = wid >> 1;   // 0..1 (M-half of tile)
  const int wc   = wid & 1;    // 0..1 (N-half of tile)
  const int r16  = lane & 15;
  const int g4   = lane >> 4;  // k-chunk 0..3

  const int srow = tid >> 2;           // 0..63
  const int skch = (tid & 3) * 16;     // 0..48 bytes

  // ---- super-tile mapping: grid 8192 = 64 bm x 128 bn; 8 XCD patches of
  // 32x32 blocks (2x4 patch grid). Concurrent ~2 bm-rows x 32 bn per XCD:
  // X panels L2-resident, W via L3; union = X+W = 192 MB < L3.
  const int bid = blockIdx.x;
  const int xcd = bid & 7;
  const int l   = bid >> 3;            // 0..1023
  const int bm  = (xcd & 1) * 32 + (l >> 5);
  const int bn  = (xcd >> 1) * 32 + (l & 31);

  f32x4 acc[4][4];
#pragma unroll
  for (int i = 0; i < 4; ++i)
#pragma unroll
    for (int j = 0; j < 4; ++j) acc[i][j] = (f32x4)0.f;

  bf16x8s pa[4], qa[4], pb[4], qb[4];

  const char* Xp = (const char*)Xb + (size_t)(bm * 128) * RSB;
  const char* Wp = (const char*)Wb + (size_t)(bn * 128) * RSB;

  // Fragment base addresses: A row = wr*64 + mi*16 + r16, col = g4*16
  const uint32_t ldsb = (uint32_t)(uintptr_t)(void*)lds;
  const uint32_t aoff = ldsb + (uint32_t)((wr * 64 + r16) * 64 + g4 * 16);
  const uint32_t boff =
      ldsb + (uint32_t)(16384 + (wc * 64 + r16) * 64 + g4 * 16);

  // ---- prologue: stage (0,k0),(0,k1),(1,k0); confirm (0,*); read (0,k0) ----
  STAGE(Xp, 0,   ABLK(lds, 0));
  STAGE(Wp, 0,   BBLK(lds, 0));
  STAGE(Xp, 64,  ABLK(lds, 1));
  STAGE(Wp, 64,  BBLK(lds, 1));
  STAGE(Xp, 128, ABLK(lds + 32768, 0));
  STAGE(Wp, 128, BBLK(lds + 32768, 0));
  WAIT4;        // 12 -> 4: confirms (0,k0) and (0,k1)
  BARRIER();
  READ8(pa, pb, 0u);   // (0,k0); loop's first WAITL0 drains these

  // ---- main loop: tiles 0 .. NT-3 ----
  for (int t = 0; t <= NT - 3; ++t) {
    const uint32_t cur = (uint32_t)(t & 1) << 15;
    const uint32_t nxt = cur ^ 32768u;
    char* cb = lds + cur;
    char* nb = lds + nxt;
    const size_t k1n = (size_t)(t + 1) * 128;
    const size_t k2n = (size_t)(t + 2) * 128;
    // epoch A: MFMA (t,k0)=P; interleave-prefetch Q<-(t,k1); stage (t+1,k1)
    STAGE(Xp, k1n + 64, ABLK(nb, 1));
    STAGE(Wp, k1n + 64, BBLK(nb, 1));
    WAITL0;     // P frags landed (issued interleaved during prev epoch)
    EPOCH_ILV(pa, pb, qa, qb, cur + 8192u);
    WAIT4;      // confirms (t+1,k0), staged one epoch ago
    BARRIER();
    // epoch B: MFMA (t,k1)=Q; interleave-prefetch P<-(t+1,k0); stage (t+2,k0)
    STAGE(Xp, k2n, ABLK(cb, 0));
    STAGE(Wp, k2n, BBLK(cb, 0));
    WAITL0;
    EPOCH_ILV(qa, qb, pa, pb, nxt);
    WAIT4;      // confirms (t+1,k1)
    BARRIER();
  }

  // ---- tail: tile NT-2 (even; cur=buf0, nxt=buf1) ----
  {
    const uint32_t cur = (uint32_t)((NT - 2) & 1) << 15;
    const uint32_t nxt = cur ^ 32768u;
    char* nb = lds + nxt;
    const size_t k1n = (size_t)(NT - 1) * 128;
    // epoch A: MFMA (NT-2,k0); prefetch (NT-2,k1); stage (NT-1,k1)
    STAGE(Xp, k1n + 64, ABLK(nb, 1));
    STAGE(Wp, k1n + 64, BBLK(nb, 1));
    WAITL0;
    EPOCH_ILV(pa, pb, qa, qb, cur + 8192u);
    WAIT4;      // confirms (NT-1,k0)
    BARRIER();
    // epoch B: MFMA (NT-2,k1); prefetch (NT-1,k0); no stage
    WAITL0;
    EPOCH_ILV(qa, qb, pa, pb, nxt);
    WAIT0;      // confirms (NT-1,k1)
    BARRIER();
    // tile NT-1, epoch A: MFMA (NT-1,k0); prefetch (NT-1,k1)
    WAITL0;
    EPOCH_ILV(pa, pb, qa, qb, nxt + 8192u);
    // tile NT-1, epoch B: MFMA (NT-1,k1)
    WAITL0;
    MFMA16(qa, qb);
  }

  // ---- epilogue: y = scale*acc + bias ----
  // C/D layout: col = lane&15, row = (lane>>4)*4 + reg  [m89/m91-verified]
  const float s = scalep[0];
  float bv[4];
#pragma unroll
  for (int ni = 0; ni < 4; ++ni)
    bv[ni] = bias[bn * 128 + wc * 64 + ni * 16 + r16];

#pragma unroll
  for (int mi = 0; mi < 4; ++mi) {
    const int grow0 = bm * 128 + wr * 64 + mi * 16 + g4 * 4;
#pragma unroll
    for (int r = 0; r < 4; ++r) {
      float* yp = Y + (size_t)(grow0 + r) * N + bn * 128 + wc * 64 + r16;
#pragma unroll
      for (int ni = 0; ni < 4; ++ni)
        yp[ni * 16] = s * acc[mi][ni][r] + bv[ni];
    }
  }
}

// ---------------- fallback: fused kernel (if ws too small) ----------------
#define BM 128
#define BN 128
#define BK 64
#define LDKF (BK * 2)

__global__ __launch_bounds__(256, 2) void qlinear_fused_kernel(
    const float* __restrict__ X, const int32_t* __restrict__ W,
    const float* __restrict__ scalep, const float* __restrict__ bias,
    float* __restrict__ Y)
{
  constexpr int N = 16384, K = 4096;
  __shared__ __align__(16) char slds[(BM + BN) * LDKF];
  char* As = slds;
  char* Bs = slds + BM * LDKF;
  const int tid = threadIdx.x, lane = tid & 63, wid = tid >> 6;
  const int wr = wid >> 1, wc = wid & 1;
  const int nwg = gridDim.x, cpx = nwg >> 3, bid = blockIdx.x;
  const int swz = (bid & 7) * cpx + (bid >> 3);
  const int ntn = N / BN, bm = swz / ntn, bn = swz % ntn;
  const int r16 = lane & 15, g4 = lane >> 4;
  f32x4 acc[4][4];
#pragma unroll
  for (int i = 0; i < 4; ++i)
#pragma unroll
    for (int j = 0; j < 4; ++j) acc[i][j] = (f32x4)0.f;
  const float* Abase = X + (size_t)(bm * BM) * K;
  const int32_t* Bbase = W + (size_t)(bn * BN) * K;
  const int stg_col = (tid & 7) * 8;
  for (int kt = 0; kt < K / BK; ++kt) {
    const int kb = kt * BK;
    if (kt) __syncthreads();
#pragma unroll
    for (int i = 0; i < 4; ++i) {
      const int row = i * 32 + (tid >> 3);
      const float* p = Abase + (size_t)row * K + kb + stg_col;
      f32x4 v0 = *(const f32x4*)p;
      f32x4 v1 = *(const f32x4*)(p + 4);
      u32x4 o = {pk2_rne(v0.x, v0.y), pk2_rne(v0.z, v0.w),
                 pk2_rne(v1.x, v1.y), pk2_rne(v1.z, v1.w)};
      int byte = (row * LDKF + stg_col * 2) ^ ((row & 7) << 4);
      *(u32x4*)(As + byte) = o;
    }
#pragma unroll
    for (int i = 0; i < 4; ++i) {
      const int row = i * 32 + (tid >> 3);
      const int32_t* p = Bbase + (size_t)row * K + kb + stg_col;
      i32x4 v0 = *(const i32x4*)p;
      i32x4 v1 = *(const i32x4*)(p + 4);
      u32x4 o = {pk2_trunc((float)v0.x, (float)v0.y),
                 pk2_trunc((float)v0.z, (float)v0.w),
                 pk2_trunc((float)v1.x, (float)v1.y),
                 pk2_trunc((float)v1.z, (float)v1.w)};
      int byte = (row * LDKF + stg_col * 2) ^ ((row & 7) << 4);
      *(u32x4*)(Bs + byte) = o;
    }
    __syncthreads();
#pragma unroll
    for (int kk = 0; kk < 2; ++kk) {
      bf16x8s af[4], bfr[4];
#pragma unroll
      for (int mi = 0; mi < 4; ++mi) {
        const int row = wr * 64 + mi * 16 + r16;
        int byte = (row * LDKF + kk * 64 + g4 * 16) ^ ((row & 7) << 4);
        af[mi] = *(const bf16x8s*)(As + byte);
      }
#pragma unroll
      for (int ni = 0; ni < 4; ++ni) {
        const int row = wc * 64 + ni * 16 + r16;
        int byte = (row * LDKF + kk * 64 + g4 * 16) ^ ((row & 7) << 4);
        bfr[ni] = *(const bf16x8s*)(Bs + byte);
      }
#pragma unroll
      for (int mi = 0; mi < 4; ++mi)
#pragma unroll
        for (int ni = 0; ni < 4; ++ni)
          acc[mi][ni] = __builtin_amdgcn_mfma_f32_16x16x32_bf16(
              af[mi], bfr[ni], acc[mi][ni], 0, 0, 0);
    }
  }
  const float s = scalep[0];
  float bv[4];
#pragma unroll
  for (int ni = 0; ni < 4; ++ni)
    bv[ni] = bias[bn * BN + wc * 64 + ni * 16 + r16];
#pragma unroll
  for (int mi = 0; mi < 4; ++mi) {
    const int grow0 = bm * BM + wr * 64 + mi * 16 + g4 * 4;
#pragma unroll
    for (int r = 0; r < 4; ++r) {
      float* yp = Y + (size_t)(grow0 + r) * N + bn * BN + wc * 64 + r16;
#pragma unroll
      for (int ni = 0; ni < 4; ++ni)
        yp[ni * 16] = s * acc[mi][ni][r] + bv[ni];
    }
  }
}

extern "C" void kernel_launch(void* const* d_in, const int* in_sizes, int n_in,
                              void* d_out, int out_size, void* d_ws, size_t ws_size,
                              hipStream_t stream) {
  const float*   x  = (const float*)d_in[0];
  const int32_t* w  = (const int32_t*)d_in[1];
  const float*   sc = (const float*)d_in[2];
  const float*   bs = (const float*)d_in[3];
  float*         y  = (float*)d_out;

  constexpr size_t M = 8192, N = 16384, K = 4096;
  const size_t xb_elems = M * K;   // 64 MB bf16
  const size_t wb_elems = N * K;   // 128 MB bf16
  const size_t need = (xb_elems + wb_elems) * 2;

  if (ws_size >= need) {
    uint16_t* xb = (uint16_t*)d_ws;
    uint16_t* wb = xb + xb_elems;
    hipFuncSetAttribute((const void*)qlinear_gemm_128_kernel,
                        hipFuncAttributeMaxDynamicSharedMemorySize, 65536);
    conv_x_kernel<<<2048, 256, 0, stream>>>(x, xb, (int)(xb_elems / 8));
    conv_w_kernel<<<2048, 256, 0, stream>>>(w, wb, (int)(wb_elems / 8));
    // grid = (M/128) * (N/128) = 64 * 128 = 8192 blocks, 256 threads
    qlinear_gemm_128_kernel<<<8192, 256, 65536, stream>>>(xb, wb, sc, bs, y);
  } else {
    qlinear_fused_kernel<<<8192, 256, 0, stream>>>(x, w, sc, bs, y);
  }
}

// Round 15
// 605.036 us; speedup vs baseline: 2.4513x; 2.4513x over previous
//
#include <hip/hip_runtime.h>
#include <hip/hip_bf16.h>
#include <stdint.h>

// QuantizedLinear: Y[M][N] = scale * (X[M][K] @ W[N][K]^T) + bias[N]
// M=8192, K=4096, N=16384. X fp32, W int32 (harness widens int8), out fp32.
// Round 15: int8 MFMA path. W is exactly representable in i8; x gets
// per-row dynamic symmetric quantization (Delta_r = rowmax/127). GEMM is
// the r11 structure verbatim (proven best: 0 bank conflicts via XOR chunk
// swizzle, counted-vmcnt ring, DS||MFMA interleave) with i8 frags and
// mfma_i32_16x16x64_i8 (K=64/instr -> half the epochs of the bf16 path).
// Epilogue: y = (float)acc_i32 * (s * Delta_row) + bias.
// Pre-committed: if absmax > threshold, revert to r11 next round.

typedef __attribute__((ext_vector_type(4))) float f32x4;
typedef __attribute__((ext_vector_type(4))) int i32x4;
typedef __attribute__((ext_vector_type(8))) short bf16x8s;
typedef __attribute__((ext_vector_type(4))) unsigned int u32x4;

__device__ __forceinline__ uint32_t f2bf_rne(float f) {
  uint32_t x = __float_as_uint(f);
  return (x + 0x7FFFu + ((x >> 16) & 1u)) >> 16;
}
__device__ __forceinline__ uint32_t pk2_rne(float lo, float hi) {
  return f2bf_rne(lo) | (f2bf_rne(hi) << 16);
}
__device__ __forceinline__ uint32_t pk2_trunc(float lo, float hi) {
  return (__float_as_uint(lo) >> 16) | (__float_as_uint(hi) & 0xFFFF0000u);
}

#define GLOAD_LDS16(g, l)                                        \
  __builtin_amdgcn_global_load_lds(                              \
      (const __attribute__((address_space(1))) void*)(g),        \
      (__attribute__((address_space(3))) void*)(l), 16, 0, 0)

// ---------------- quantization kernels ----------------
// Per-row x quant: one block per row. Pass: 16 f32/thread (coalesced),
// wave shuffle max -> LDS -> rowmax; quantize+pack; rscale[r] = rowmax/127.
__global__ __launch_bounds__(256) void quant_x_kernel(
    const float* __restrict__ x, int8_t* __restrict__ xq,
    float* __restrict__ rscale) {
  const int r = blockIdx.x;
  const int t = threadIdx.x;
  const f32x4* rp = (const f32x4*)(x + (size_t)r * 4096);
  f32x4 v[4];
#pragma unroll
  for (int j = 0; j < 4; ++j)
    v[j] = __builtin_nontemporal_load(rp + t + 256 * j);
  float m = 0.f;
#pragma unroll
  for (int j = 0; j < 4; ++j) {
    m = fmaxf(m, fabsf(v[j].x));
    m = fmaxf(m, fabsf(v[j].y));
    m = fmaxf(m, fabsf(v[j].z));
    m = fmaxf(m, fabsf(v[j].w));
  }
#pragma unroll
  for (int off = 32; off >= 1; off >>= 1)
    m = fmaxf(m, __shfl_xor(m, off, 64));
  __shared__ float wm[4];
  if ((t & 63) == 0) wm[t >> 6] = m;
  __syncthreads();
  float mm = fmaxf(fmaxf(wm[0], wm[1]), fmaxf(wm[2], wm[3]));
  mm = fmaxf(mm, 1e-20f);
  const float inv = 127.0f / mm;
  if (t == 0) rscale[r] = mm * (1.0f / 127.0f);
  uint32_t* orow = (uint32_t*)(xq + (size_t)r * 4096);
#pragma unroll
  for (int j = 0; j < 4; ++j) {
    int q0 = (int)rintf(v[j].x * inv);
    int q1 = (int)rintf(v[j].y * inv);
    int q2 = (int)rintf(v[j].z * inv);
    int q3 = (int)rintf(v[j].w * inv);
    q0 = max(-127, min(127, q0)); q1 = max(-127, min(127, q1));
    q2 = max(-127, min(127, q2)); q3 = max(-127, min(127, q3));
    uint32_t o = (uint32_t)(q0 & 0xFF) | ((uint32_t)(q1 & 0xFF) << 8) |
                 ((uint32_t)(q2 & 0xFF) << 16) | ((uint32_t)(q3 & 0xFF) << 24);
    orow[t + 256 * j] = o;
  }
}

// W int32 -> int8 (exact): 16 elems/thread, grid-stride.
__global__ __launch_bounds__(256) void conv_w_q_kernel(
    const int32_t* __restrict__ w, int8_t* __restrict__ wq, int n16) {
  const int stride = blockDim.x * gridDim.x;
  for (int i = blockIdx.x * blockDim.x + threadIdx.x; i < n16; i += stride) {
    u32x4 o;
#pragma unroll
    for (int j = 0; j < 4; ++j) {
      i32x4 a = __builtin_nontemporal_load((const i32x4*)w + i * 4 + j);
      uint32_t p = (uint32_t)(a.x & 0xFF) | ((uint32_t)(a.y & 0xFF) << 8) |
                   ((uint32_t)(a.z & 0xFF) << 16) |
                   ((uint32_t)(a.w & 0xFF) << 24);
      if (j == 0) o.x = p; else if (j == 1) o.y = p;
      else if (j == 2) o.z = p; else o.w = p;
    }
    ((u32x4*)wq)[i] = o;
  }
}

// ---------------- 256x256 i8 GEMM (r11 structure, byte-identical LDS) -----
// LDS: buf b at b*65536; A at +0, B at +32768; K-half kk at kk*16384 =
// [256 rows][64 B] (64 i8 k-elems). Swizzle: chunk ^= (row>>1)&3
// (involution), pre-swizzled GLOBAL source + linear LDS dest (rule #21).
// Tile BK = 128 elems (2 k-slots); NT = 32. Per epoch: 12 ds_read_b128
// (8 A-frags, 4 B-frags) + 32 mfma_i32_16x16x64_i8, r11 interleave.

#define PIN() __builtin_amdgcn_sched_barrier(0)

#define BARRIER()                 \
  PIN();                          \
  __builtin_amdgcn_s_barrier();   \
  PIN()

#define WAIT4  asm volatile("s_waitcnt vmcnt(4)" ::: "memory"); PIN()
#define WAIT0  asm volatile("s_waitcnt vmcnt(0)" ::: "memory"); PIN()
#define WAITL0 asm volatile("s_waitcnt lgkmcnt(0)" ::: "memory"); PIN()

#define STAGE(mat_base, koffb, ldsbase)                                      \
  {                                                                          \
    GLOAD_LDS16((mat_base) + (size_t)srow * RSB + (koffb) + skch,            \
                (ldsbase) + tid * 16);                                       \
    GLOAD_LDS16((mat_base) + (size_t)(srow + 128) * RSB + (koffb) + skch,    \
                (ldsbase) + 8192 + tid * 16);                                \
  }

#define ABLK(buf, kk) ((buf) + (kk) * 16384)
#define BBLK(buf, kk) ((buf) + 32768 + (kk) * 16384)

#define DSR(dst, addr, OFF)                                                  \
  asm volatile("ds_read_b128 %0, %1 offset:" OFF : "=v"(dst) : "v"(addr))

#define READ12(da, db, blkoff)                                               \
  {                                                                          \
    uint32_t _aa = aoff + (blkoff), _bb = boff + (blkoff);                   \
    DSR(da[0], _aa, "0");    DSR(da[1], _aa, "1024");                        \
    DSR(da[2], _aa, "2048"); DSR(da[3], _aa, "3072");                        \
    DSR(da[4], _aa, "4096"); DSR(da[5], _aa, "5120");                        \
    DSR(da[6], _aa, "6144"); DSR(da[7], _aa, "7168");                        \
    DSR(db[0], _bb, "0");    DSR(db[1], _bb, "1024");                        \
    DSR(db[2], _bb, "2048"); DSR(db[3], _bb, "3072");                        \
  }

#define MFMA4(av, bv, j)                                                     \
  _Pragma("unroll") for (int ni = 0; ni < 4; ++ni)                           \
    acc[j][ni] = __builtin_amdgcn_mfma_i32_16x16x64_i8(                      \
        av[j], bv[ni], acc[j][ni], 0, 0, 0);

#define EPOCH_ILV(av, bv, xa, xb, blkoff)                                    \
  {                                                                          \
    uint32_t _aa = aoff + (blkoff), _bb = boff + (blkoff);                   \
    __builtin_amdgcn_s_setprio(1);                                           \
    DSR(xa[0], _aa, "0");    DSR(xa[1], _aa, "1024");   PIN();               \
    MFMA4(av, bv, 0);                                   PIN();               \
    DSR(xa[2], _aa, "2048"); DSR(xa[3], _aa, "3072");   PIN();               \
    MFMA4(av, bv, 1);                                   PIN();               \
    DSR(xa[4], _aa, "4096"); DSR(xa[5], _aa, "5120");   PIN();               \
    MFMA4(av, bv, 2);                                   PIN();               \
    DSR(xa[6], _aa, "6144"); DSR(xa[7], _aa, "7168");   PIN();               \
    MFMA4(av, bv, 3);                                   PIN();               \
    DSR(xb[0], _bb, "0");    DSR(xb[1], _bb, "1024");   PIN();               \
    MFMA4(av, bv, 4);                                   PIN();               \
    DSR(xb[2], _bb, "2048"); DSR(xb[3], _bb, "3072");   PIN();               \
    MFMA4(av, bv, 5);                                   PIN();               \
    MFMA4(av, bv, 6);                                                        \
    MFMA4(av, bv, 7);                                                        \
    __builtin_amdgcn_s_setprio(0);                                           \
  }

#define MFMA32(av, bv)                                                       \
  __builtin_amdgcn_s_setprio(1);                                             \
  _Pragma("unroll") for (int j = 0; j < 8; ++j)                              \
    _Pragma("unroll") for (int ni = 0; ni < 4; ++ni)                         \
      acc[j][ni] = __builtin_amdgcn_mfma_i32_16x16x64_i8(                    \
          av[j], bv[ni], acc[j][ni], 0, 0, 0);                               \
  __builtin_amdgcn_s_setprio(0);

__global__ __launch_bounds__(512, 2) void qlinear_gemm_i8_kernel(
    const int8_t* __restrict__ Xq,   // [M][K] i8
    const int8_t* __restrict__ Wq,   // [N][K] i8
    const float* __restrict__ rscale,  // [M] per-row Delta
    const float* __restrict__ scalep,
    const float* __restrict__ bias,
    float* __restrict__ Y)
{
  constexpr int N = 16384, K = 4096;
  constexpr int RSB = K;       // panel row stride, bytes (i8)
  constexpr int NT = K / 128;  // 32 K-tiles (128 elems = 128 B each)

  extern __shared__ __align__(16) char lds[];  // 131072 B

  const int tid  = threadIdx.x;
  const int lane = tid & 63;
  const int wid  = tid >> 6;   // 0..7
  const int wm   = wid >> 2;   // 0..1  (M-half of block)
  const int wn   = wid & 3;    // 0..3  (N-quarter of block)
  const int r16  = lane & 15;
  const int g4   = lane >> 4;  // logical k-chunk 0..3 (16 B = 16 elems)
  const int chb  = (g4 ^ ((r16 >> 1) & 3)) << 4;  // swizzled chunk byte off

  const int srow = tid >> 2;                              // 0..127
  const int skch = ((tid & 3) ^ ((tid >> 3) & 3)) * 16;   // pre-swizzled src

  // ---- 2D super-tile mapping (round 6): XCD-private 16x16 patches ----
  const int bid = blockIdx.x;
  const int xcd = bid & 7;
  const int l   = bid >> 3;          // 0..255
  const int bm  = (xcd & 1) * 16 + (l >> 4);
  const int bn  = (xcd >> 1) * 16 + (l & 15);

  i32x4 acc[8][4];
#pragma unroll
  for (int i = 0; i < 8; ++i)
#pragma unroll
    for (int j = 0; j < 4; ++j) acc[i][j] = (i32x4)0;

  i32x4 pa[8], qa[8], pb[4], qb[4];

  const char* Xp = (const char*)Xq + (size_t)(bm * 256) * RSB;
  const char* Wp = (const char*)Wq + (size_t)(bn * 256) * RSB;

  const uint32_t ldsb = (uint32_t)(uintptr_t)(void*)lds;
  const uint32_t aoff = ldsb + (uint32_t)((wm * 128 + r16) * 64 + chb);
  const uint32_t boff = ldsb + (uint32_t)(32768 + (wn * 64 + r16) * 64 + chb);

  // ---- prologue: stage (0,k0),(0,k1),(1,k0); confirm (0,*); read (0,k0) ----
  STAGE(Xp, 0,   ABLK(lds, 0));
  STAGE(Wp, 0,   BBLK(lds, 0));
  STAGE(Xp, 64,  ABLK(lds, 1));
  STAGE(Wp, 64,  BBLK(lds, 1));
  STAGE(Xp, 128, ABLK(lds + 65536, 0));
  STAGE(Wp, 128, BBLK(lds + 65536, 0));
  WAIT4;        // 12 -> 4: confirms (0,k0) and (0,k1)
  BARRIER();
  READ12(pa, pb, 0u);   // (0,k0)

  // ---- main loop: tiles 0 .. NT-3 ----
  for (int t = 0; t <= NT - 3; ++t) {
    const uint32_t cur = (uint32_t)(t & 1) << 16;
    const uint32_t nxt = cur ^ 65536u;
    char* cb = lds + cur;
    char* nb = lds + nxt;
    const size_t k1n = (size_t)(t + 1) * 128;
    const size_t k2n = (size_t)(t + 2) * 128;
    // epoch A: MFMA (t,k0)=P; interleave-prefetch Q<-(t,k1); stage (t+1,k1)
    STAGE(Xp, k1n + 64, ABLK(nb, 1));
    STAGE(Wp, k1n + 64, BBLK(nb, 1));
    WAITL0;
    EPOCH_ILV(pa, pb, qa, qb, cur + 16384u);
    WAIT4;      // confirms (t+1,k0)
    BARRIER();
    // epoch B: MFMA (t,k1)=Q; interleave-prefetch P<-(t+1,k0); stage (t+2,k0)
    STAGE(Xp, k2n, ABLK(cb, 0));
    STAGE(Wp, k2n, BBLK(cb, 0));
    WAITL0;
    EPOCH_ILV(qa, qb, pa, pb, nxt);
    WAIT4;      // confirms (t+1,k1)
    BARRIER();
  }

  // ---- tail: tile NT-2 ----
  {
    const uint32_t cur = (uint32_t)((NT - 2) & 1) << 16;
    const uint32_t nxt = cur ^ 65536u;
    char* nb = lds + nxt;
    const size_t k1n = (size_t)(NT - 1) * 128;
    STAGE(Xp, k1n + 64, ABLK(nb, 1));
    STAGE(Wp, k1n + 64, BBLK(nb, 1));
    WAITL0;
    EPOCH_ILV(pa, pb, qa, qb, cur + 16384u);
    WAIT4;      // confirms (NT-1,k0)
    BARRIER();
    WAITL0;
    EPOCH_ILV(qa, qb, pa, pb, nxt);
    WAIT0;      // confirms (NT-1,k1)
    BARRIER();
    WAITL0;
    EPOCH_ILV(pa, pb, qa, qb, nxt + 16384u);
    WAITL0;
    MFMA32(qa, qb);
  }

  // ---- epilogue: y = (float)acc * (s*Delta_row) + bias ----
  // C/D layout: col = lane&15, row = (lane>>4)*4 + reg (dtype-independent)
  const float s = scalep[0];
  float bv[4];
#pragma unroll
  for (int ni = 0; ni < 4; ++ni)
    bv[ni] = bias[bn * 256 + wn * 64 + ni * 16 + r16];

#pragma unroll
  for (int mi = 0; mi < 8; ++mi) {
    const int grow0 = bm * 256 + wm * 128 + mi * 16 + g4 * 4;
#pragma unroll
    for (int r = 0; r < 4; ++r) {
      const float dr = s * rscale[grow0 + r];
      float* yp = Y + (size_t)(grow0 + r) * N + bn * 256 + wn * 64 + r16;
#pragma unroll
      for (int ni = 0; ni < 4; ++ni)
        yp[ni * 16] = (float)acc[mi][ni][r] * dr + bv[ni];
    }
  }
}

// ---------------- fallback: fused bf16 kernel (if ws too small) ------------
#define BM 128
#define BN 128
#define BK 64
#define LDKF (BK * 2)

__global__ __launch_bounds__(256, 2) void qlinear_fused_kernel(
    const float* __restrict__ X, const int32_t* __restrict__ W,
    const float* __restrict__ scalep, const float* __restrict__ bias,
    float* __restrict__ Y)
{
  constexpr int N = 16384, K = 4096;
  __shared__ __align__(16) char slds[(BM + BN) * LDKF];
  char* As = slds;
  char* Bs = slds + BM * LDKF;
  const int tid = threadIdx.x, lane = tid & 63, wid = tid >> 6;
  const int wr = wid >> 1, wc = wid & 1;
  const int nwg = gridDim.x, cpx = nwg >> 3, bid = blockIdx.x;
  const int swz = (bid & 7) * cpx + (bid >> 3);
  const int ntn = N / BN, bm = swz / ntn, bn = swz % ntn;
  const int r16 = lane & 15, g4 = lane >> 4;
  f32x4 acc[4][4];
#pragma unroll
  for (int i = 0; i < 4; ++i)
#pragma unroll
    for (int j = 0; j < 4; ++j) acc[i][j] = (f32x4)0.f;
  const float* Abase = X + (size_t)(bm * BM) * K;
  const int32_t* Bbase = W + (size_t)(bn * BN) * K;
  const int stg_col = (tid & 7) * 8;
  for (int kt = 0; kt < K / BK; ++kt) {
    const int kb = kt * BK;
    if (kt) __syncthreads();
#pragma unroll
    for (int i = 0; i < 4; ++i) {
      const int row = i * 32 + (tid >> 3);
      const float* p = Abase + (size_t)row * K + kb + stg_col;
      f32x4 v0 = *(const f32x4*)p;
      f32x4 v1 = *(const f32x4*)(p + 4);
      u32x4 o = {pk2_rne(v0.x, v0.y), pk2_rne(v0.z, v0.w),
                 pk2_rne(v1.x, v1.y), pk2_rne(v1.z, v1.w)};
      int byte = (row * LDKF + stg_col * 2) ^ ((row & 7) << 4);
      *(u32x4*)(As + byte) = o;
    }
#pragma unroll
    for (int i = 0; i < 4; ++i) {
      const int row = i * 32 + (tid >> 3);
      const int32_t* p = Bbase + (size_t)row * K + kb + stg_col;
      i32x4 v0 = *(const i32x4*)p;
      i32x4 v1 = *(const i32x4*)(p + 4);
      u32x4 o = {pk2_trunc((float)v0.x, (float)v0.y),
                 pk2_trunc((float)v0.z, (float)v0.w),
                 pk2_trunc((float)v1.x, (float)v1.y),
                 pk2_trunc((float)v1.z, (float)v1.w)};
      int byte = (row * LDKF + stg_col * 2) ^ ((row & 7) << 4);
      *(u32x4*)(Bs + byte) = o;
    }
    __syncthreads();
#pragma unroll
    for (int kk = 0; kk < 2; ++kk) {
      bf16x8s af[4], bfr[4];
#pragma unroll
      for (int mi = 0; mi < 4; ++mi) {
        const int row = wr * 64 + mi * 16 + r16;
        int byte = (row * LDKF + kk * 64 + g4 * 16) ^ ((row & 7) << 4);
        af[mi] = *(const bf16x8s*)(As + byte);
      }
#pragma unroll
      for (int ni = 0; ni < 4; ++ni) {
        const int row = wc * 64 + ni * 16 + r16;
        int byte = (row * LDKF + kk * 64 + g4 * 16) ^ ((row & 7) << 4);
        bfr[ni] = *(const bf16x8s*)(Bs + byte);
      }
#pragma unroll
      for (int mi = 0; mi < 4; ++mi)
#pragma unroll
        for (int ni = 0; ni < 4; ++ni)
          acc[mi][ni] = __builtin_amdgcn_mfma_f32_16x16x32_bf16(
              af[mi], bfr[ni], acc[mi][ni], 0, 0, 0);
    }
  }
  const float s = scalep[0];
  float bv[4];
#pragma unroll
  for (int ni = 0; ni < 4; ++ni)
    bv[ni] = bias[bn * BN + wc * 64 + ni * 16 + r16];
#pragma unroll
  for (int mi = 0; mi < 4; ++mi) {
    const int grow0 = bm * BM + wr * 64 + mi * 16 + g4 * 4;
#pragma unroll
    for (int r = 0; r < 4; ++r) {
      float* yp = Y + (size_t)(grow0 + r) * N + bn * BN + wc * 64 + r16;
#pragma unroll
      for (int ni = 0; ni < 4; ++ni)
        yp[ni * 16] = s * acc[mi][ni][r] + bv[ni];
    }
  }
}

extern "C" void kernel_launch(void* const* d_in, const int* in_sizes, int n_in,
                              void* d_out, int out_size, void* d_ws, size_t ws_size,
                              hipStream_t stream) {
  const float*   x  = (const float*)d_in[0];
  const int32_t* w  = (const int32_t*)d_in[1];
  const float*   sc = (const float*)d_in[2];
  const float*   bs = (const float*)d_in[3];
  float*         y  = (float*)d_out;

  constexpr size_t M = 8192, N = 16384, K = 4096;
  const size_t wq_bytes = N * K;        // 67.1 MB
  const size_t xq_bytes = M * K;        // 33.6 MB
  const size_t need = wq_bytes + xq_bytes + M * sizeof(float);

  if (ws_size >= need) {
    int8_t* wq = (int8_t*)d_ws;
    int8_t* xq = wq + wq_bytes;
    float*  rs = (float*)(xq + xq_bytes);
    hipFuncSetAttribute((const void*)qlinear_gemm_i8_kernel,
                        hipFuncAttributeMaxDynamicSharedMemorySize, 131072);
    quant_x_kernel<<<8192, 256, 0, stream>>>(x, xq, rs);
    conv_w_q_kernel<<<2048, 256, 0, stream>>>(w, wq, (int)(wq_bytes / 16));
    qlinear_gemm_i8_kernel<<<2048, 512, 131072, stream>>>(xq, wq, rs, sc, bs, y);
  } else {
    qlinear_fused_kernel<<<8192, 256, 0, stream>>>(x, w, sc, bs, y);
  }
}